// Round 1
// baseline (26460.153 us; speedup 1.0000x reference)
//
#include <hip/hip_runtime.h>
#include <math.h>

#define T_STEPS 128
#define BATCH   512
#define NTOK    512
#define NINP    512
#define NHID    600
#define NBK     6
#define BS      100
#define HH      4
#define DK      64
#define DV      85
#define ATT     340
#define H2      4
#define DK2     32
#define DV2     32
#define KVN     596     // H*DK + H*DV = 256 + 340
#define G3      300     // 3*BS
#define CHUNK   8

__device__ __forceinline__ float sigf(float x) { return 1.f / (1.f + expf(-x)); }

// ---------------- generic tiled fp32 GEMM: C = A@W (+bias) ----------------
__device__ __forceinline__ void gemm_tile(const float* __restrict__ A, int lda,
                                          const float* __restrict__ W, int ldw,
                                          const float* __restrict__ bias,
                                          float* __restrict__ C, int ldc,
                                          int M, int N, int K, int m0, int n0)
{
    __shared__ __align__(16) float As[16][68];
    __shared__ __align__(16) float Ws[16][68];
    const int tid = threadIdx.x;                  // 256 threads
    const int tm = (tid >> 4) << 2;               // 0..60
    const int tn = (tid & 15) << 2;               // 0..60
    float acc[4][4];
#pragma unroll
    for (int i = 0; i < 4; i++)
#pragma unroll
        for (int j = 0; j < 4; j++) acc[i][j] = 0.f;

    for (int k0 = 0; k0 < K; k0 += 16) {
#pragma unroll
        for (int e = 0; e < 4; e++) {
            int idx = (e << 8) + tid;             // 0..1023
            int kk = idx & 15, mm = idx >> 4;
            int gm = m0 + mm, gk = k0 + kk;
            As[kk][mm] = (gm < M && gk < K) ? A[(size_t)gm * lda + gk] : 0.f;
            int nn = idx & 63, k2 = idx >> 6;
            int gn = n0 + nn, gk2 = k0 + k2;
            Ws[k2][nn] = (gn < N && gk2 < K) ? W[(size_t)gk2 * ldw + gn] : 0.f;
        }
        __syncthreads();
#pragma unroll
        for (int kk = 0; kk < 16; kk++) {
            float a0 = As[kk][tm+0], a1 = As[kk][tm+1], a2 = As[kk][tm+2], a3 = As[kk][tm+3];
            float w0 = Ws[kk][tn+0], w1 = Ws[kk][tn+1], w2 = Ws[kk][tn+2], w3 = Ws[kk][tn+3];
            acc[0][0] += a0*w0; acc[0][1] += a0*w1; acc[0][2] += a0*w2; acc[0][3] += a0*w3;
            acc[1][0] += a1*w0; acc[1][1] += a1*w1; acc[1][2] += a1*w2; acc[1][3] += a1*w3;
            acc[2][0] += a2*w0; acc[2][1] += a2*w1; acc[2][2] += a2*w2; acc[2][3] += a2*w3;
            acc[3][0] += a3*w0; acc[3][1] += a3*w1; acc[3][2] += a3*w2; acc[3][3] += a3*w3;
        }
        __syncthreads();
    }
#pragma unroll
    for (int i = 0; i < 4; i++) {
        int gm = m0 + tm + i;
        if (gm < M) {
#pragma unroll
            for (int j = 0; j < 4; j++) {
                int gn = n0 + tn + j;
                if (gn < N) {
                    float v = acc[i][j];
                    if (bias) v += bias[gn];
                    C[(size_t)gm * ldc + gn] = v;
                }
            }
        }
    }
}

__global__ __launch_bounds__(256) void gemm_sb(const float* __restrict__ A, long aB, int lda,
                                               const float* __restrict__ W, long wB, int ldw,
                                               const float* __restrict__ bias, long bB,
                                               float* __restrict__ C, long cB, int ldc,
                                               int M, int N, int K)
{
    int z = blockIdx.z;
    gemm_tile(A + (size_t)z * aB, lda, W + (size_t)z * wB, ldw,
              bias ? bias + (size_t)z * bB : nullptr,
              C + (size_t)z * cB, ldc, M, N, K, blockIdx.y * 64, blockIdx.x * 64);
}

// gi = inp_use @ W_ih + b_ih ; gh = hb @ W_hh + b_hh   (blockIdx.z selects block & which)
__global__ __launch_bounds__(256) void gates_gemm(const float* __restrict__ inp_use,
                                                  const float* __restrict__ hb,
                                                  const float* __restrict__ W_ih,
                                                  const float* __restrict__ W_hh,
                                                  const float* __restrict__ b_ih,
                                                  const float* __restrict__ b_hh,
                                                  float* __restrict__ gi, float* __restrict__ gh)
{
    int z = blockIdx.z;
    if (z < NBK) {
        int n = z;
        gemm_tile(inp_use + n * ATT, NBK * ATT, W_ih + (size_t)n * ATT * G3, G3,
                  b_ih + n * G3, gi + n * G3, NBK * G3,
                  BATCH, G3, ATT, blockIdx.y * 64, blockIdx.x * 64);
    } else {
        int n = z - NBK;
        gemm_tile(hb + n * BS, NHID, W_hh + (size_t)n * BS * G3, G3,
                  b_hh + n * G3, gh + n * G3, NBK * G3,
                  BATCH, G3, BS, blockIdx.y * 64, blockIdx.x * 64);
    }
}

// kv bias: kvb = enc_b @ [Wk_in | Wv_in]
__global__ __launch_bounds__(256) void kvb_kernel(const float* __restrict__ enc_b,
                                                  const float* __restrict__ Wk,
                                                  const float* __restrict__ Wv,
                                                  float* __restrict__ kvb)
{
    int j = blockIdx.x * 256 + threadIdx.x;
    if (j >= KVN) return;
    float acc = 0.f;
    if (j < HH * DK) {
        for (int d = 0; d < NINP; d++) acc += enc_b[d] * Wk[d * (HH * DK) + j];
    } else {
        int c = j - HH * DK;
        for (int d = 0; d < NINP; d++) acc += enc_b[d] * Wv[d * (HH * DV) + c];
    }
    kvb[j] = acc;
}

// ---------------- per-sample input attention + top-k gating ----------------
__global__ __launch_bounds__(256) void attn_kernel(const float* __restrict__ h_src,
                                                   const float* __restrict__ masks_t,
                                                   const float* __restrict__ kv,
                                                   const float* __restrict__ Wq_in,
                                                   float* __restrict__ inp_use,
                                                   float* __restrict__ hb_out,
                                                   float* __restrict__ mask_out)
{
    const int b = blockIdx.x, tid = threadIdx.x;
    __shared__ float hb[NHID];
    __shared__ float kb[HH * DK];
    __shared__ float vb[HH * DV];
    __shared__ float qs[NBK * HH * DK];
    __shared__ float att[NBK * HH];
    __shared__ float acts[NBK];
    __shared__ float kthv;

    const float mt = masks_t[b];
    for (int i = tid; i < NHID; i += 256) {
        float v = h_src[(size_t)b * NHID + i] * mt;
        hb[i] = v;
        hb_out[(size_t)b * NHID + i] = v;
    }
    for (int i = tid; i < KVN; i += 256) {
        float v = kv[(size_t)b * KVN + i];
        if (i < HH * DK) kb[i] = v; else vb[i - HH * DK] = v;
    }
    __syncthreads();
    // q[n, tid] for tid in 0..255 (= h*64+d)
#pragma unroll
    for (int n = 0; n < NBK; n++) {
        float acc = 0.f;
        for (int d = 0; d < BS; d++) acc += hb[n * BS + d] * Wq_in[d * (HH * DK) + tid];
        qs[n * 256 + tid] = acc;
    }
    __syncthreads();
    if (tid < NBK * HH) {
        int n = tid >> 2, h = tid & 3;
        float s = 0.f;
        for (int d = 0; d < DK; d++) s += qs[n * 256 + h * DK + d] * kb[h * DK + d];
        att[tid] = sigf(s * 0.125f);     // softmax([l,0])[0] == sigmoid(l)
    }
    __syncthreads();
    if (tid < NBK)
        acts[tid] = 0.25f * (att[tid * 4] + att[tid * 4 + 1] + att[tid * 4 + 2] + att[tid * 4 + 3]);
    __syncthreads();
    if (tid == 0) {
        float a[NBK];
        for (int i = 0; i < NBK; i++) a[i] = acts[i];
        for (int i = 0; i < 4; i++) {          // partial descending selection sort
            int mx = i;
            for (int j = i + 1; j < NBK; j++) if (a[j] > a[mx]) mx = j;
            float t = a[i]; a[i] = a[mx]; a[mx] = t;
        }
        kthv = a[3];
    }
    __syncthreads();
    if (tid < NBK) mask_out[(size_t)b * NBK + tid] = (acts[tid] >= kthv) ? 1.f : 0.f;
    for (int idx = tid; idx < NBK * ATT; idx += 256) {
        int n = idx / ATT, r = idx - n * ATT;
        int h = r / DV, e = r - h * DV;
        inp_use[(size_t)b * (NBK * ATT) + idx] = att[n * 4 + h] * vb[h * DV + e];
    }
}

// ---------------- per-sample GRU pointwise + communication attention ----------------
__global__ __launch_bounds__(256) void gru_comm_kernel(const float* __restrict__ gi,
                                                       const float* __restrict__ gh,
                                                       const float* __restrict__ hb_in,
                                                       const float* __restrict__ mask_in,
                                                       const float* __restrict__ Wq_c,
                                                       const float* __restrict__ Wk_c,
                                                       const float* __restrict__ Wv_c,
                                                       const float* __restrict__ Wo_c,
                                                       float* __restrict__ h_out)
{
    const int b = blockIdx.x, tid = threadIdx.x;
    __shared__ float hn[NHID], hbs[NHID];
    __shared__ float qc[NBK * 128], kc[NBK * 128], vc[NBK * 128];
    __shared__ float lg[H2 * NBK * NBK];
    __shared__ float co[NBK * 128];
    __shared__ float mk[NBK];

    for (int i = tid; i < NHID; i += 256) {
        int n = i / BS, w = i - n * BS;
        size_t base = (size_t)b * (NBK * G3) + n * G3;
        float gr = gi[base + w] + gh[base + w];
        float gz = gi[base + BS + w] + gh[base + BS + w];
        float r = sigf(gr), z = sigf(gz);
        float ng = tanhf(gi[base + 2 * BS + w] + r * gh[base + 2 * BS + w]);
        float hbv = hb_in[(size_t)b * NHID + i];
        hbs[i] = hbv;
        hn[i] = (1.f - z) * ng + z * hbv;
    }
    if (tid < NBK) mk[tid] = mask_in[(size_t)b * NBK + tid];
    __syncthreads();
    // qc,kc,vc = hn @ {Wq_c,Wk_c,Wv_c} per block (each [100,128])
    for (int idx = tid; idx < 3 * NBK * 128; idx += 256) {
        int mat = idx / (NBK * 128), r2 = idx - mat * (NBK * 128);
        int n = r2 >> 7, c = r2 & 127;
        const float* W = (mat == 0) ? Wq_c : ((mat == 1) ? Wk_c : Wv_c);
        float acc = 0.f;
        for (int d = 0; d < BS; d++) acc += hn[n * BS + d] * W[d * 128 + c];
        float* dst = (mat == 0) ? qc : ((mat == 1) ? kc : vc);
        dst[n * 128 + c] = acc;
    }
    __syncthreads();
    if (tid < H2 * NBK * NBK) {
        int h = tid / 36, r2 = tid - h * 36, n = r2 / NBK, m = r2 - n * NBK;
        float s = 0.f;
        for (int e = 0; e < DK2; e++) s += qc[n * 128 + h * DK2 + e] * kc[m * 128 + h * DK2 + e];
        lg[h * 36 + n * NBK + m] = s * 0.17677669529663687f;   // 1/sqrt(32)
    }
    __syncthreads();
    if (tid < H2 * NBK) {
        int h = tid / NBK, n = tid - h * NBK;
        float* row = &lg[h * 36 + n * NBK];
        float mx = row[0];
        for (int m = 1; m < NBK; m++) mx = fmaxf(mx, row[m]);
        float s = 0.f;
        for (int m = 0; m < NBK; m++) { row[m] = expf(row[m] - mx); s += row[m]; }
        float inv = 1.f / s;
        for (int m = 0; m < NBK; m++) row[m] *= inv;
    }
    __syncthreads();
    for (int idx = tid; idx < NBK * 128; idx += 256) {
        int n = idx >> 7, d = idx & 127, h = d >> 5;
        float acc = 0.f;
        for (int m = 0; m < NBK; m++) acc += lg[h * 36 + n * NBK + m] * vc[m * 128 + d];
        co[idx] = acc;
    }
    __syncthreads();
    for (int i = tid; i < NHID; i += 256) {
        int n = i / BS, w = i - n * BS;
        float acc = 0.f;
        for (int d = 0; d < 128; d++) acc += co[n * 128 + d] * Wo_c[d * BS + w];
        float hc = hn[i] + acc;
        h_out[(size_t)b * NHID + i] = (mk[n] > 0.5f) ? hc : hbs[i];
    }
}

extern "C" void kernel_launch(void* const* d_in, const int* in_sizes, int n_in,
                              void* d_out, int out_size, void* d_ws, size_t ws_size,
                              hipStream_t stream)
{
    const float* input = (const float*)d_in[0];
    const float* h0    = (const float*)d_in[1];
    const float* masks = (const float*)d_in[2];
    const float* enc_W = (const float*)d_in[3];
    const float* enc_b = (const float*)d_in[4];
    const float* Wq_in = (const float*)d_in[5];
    const float* Wk_in = (const float*)d_in[6];
    const float* Wv_in = (const float*)d_in[7];
    const float* W_ih  = (const float*)d_in[8];
    const float* W_hh  = (const float*)d_in[9];
    const float* b_ih  = (const float*)d_in[10];
    const float* b_hh  = (const float*)d_in[11];
    const float* Wq_c  = (const float*)d_in[12];
    const float* Wk_c  = (const float*)d_in[13];
    const float* Wv_c  = (const float*)d_in[14];
    const float* Wo_c  = (const float*)d_in[15];
    const float* dec_W = (const float*)d_in[16];
    const float* dec_b = (const float*)d_in[17];
    float* out = (float*)d_out;

    float* ws   = (float*)d_ws;
    float* EWkv = ws;                                   // 512*596
    float* kvb  = EWkv + (size_t)NTOK * KVN;            // 640 (pad)
    float* kvch = kvb + 640;                            // CHUNK*512*596
    float* hbuf = kvch + (size_t)CHUNK * BATCH * KVN;   // 512*600
    float* inpu = hbuf + (size_t)BATCH * NHID;          // 512*2040
    float* mskb = inpu + (size_t)BATCH * NBK * ATT;     // 512*6
    float* gi   = mskb + (size_t)BATCH * NBK;           // 512*1800
    float* gh   = gi + (size_t)BATCH * NBK * G3;        // 512*1800
    float* hs   = gh + (size_t)BATCH * NBK * G3;        // CHUNK*512*600

    dim3 blk(256);

    // fused encoder->k/v weights: EWkv = enc_W @ [Wk_in | Wv_in], kvb = enc_b @ [..]
    gemm_sb<<<dim3(4, 8, 1), blk, 0, stream>>>(enc_W, 0, NINP, Wk_in, 0, HH * DK,
                                               nullptr, 0, EWkv, 0, KVN, NTOK, HH * DK, NINP);
    gemm_sb<<<dim3(6, 8, 1), blk, 0, stream>>>(enc_W, 0, NINP, Wv_in, 0, HH * DV,
                                               nullptr, 0, EWkv + HH * DK, 0, KVN, NTOK, HH * DV, NINP);
    kvb_kernel<<<dim3(3), blk, 0, stream>>>(enc_b, Wk_in, Wv_in, kvb);

    for (int c = 0; c < T_STEPS / CHUNK; c++) {
        // k,v for the whole chunk: [CHUNK*B, NTOK] @ [NTOK, 596]
        gemm_sb<<<dim3(10, (CHUNK * BATCH) / 64, 1), blk, 0, stream>>>(
            input + (size_t)c * CHUNK * BATCH * NTOK, 0, NTOK,
            EWkv, 0, KVN, kvb, 0, kvch, 0, KVN, CHUNK * BATCH, KVN, NTOK);

        for (int s = 0; s < CHUNK; s++) {
            int t = c * CHUNK + s;
            const float* hsrc = (t == 0) ? h0 : hs + (size_t)((t - 1) & (CHUNK - 1)) * BATCH * NHID;
            attn_kernel<<<dim3(BATCH), blk, 0, stream>>>(
                hsrc, masks + (size_t)t * BATCH, kvch + (size_t)s * BATCH * KVN,
                Wq_in, inpu, hbuf, mskb);
            gates_gemm<<<dim3(5, 8, 12), blk, 0, stream>>>(inpu, hbuf, W_ih, W_hh, b_ih, b_hh, gi, gh);
            gru_comm_kernel<<<dim3(BATCH), blk, 0, stream>>>(
                gi, gh, hbuf, mskb, Wq_c, Wk_c, Wv_c, Wo_c,
                hs + (size_t)s * BATCH * NHID);
        }
        // decoder for the chunk: [CHUNK*B, 600] @ [600, 512] -> d_out
        gemm_sb<<<dim3(8, (CHUNK * BATCH) / 64, 1), blk, 0, stream>>>(
            hs, 0, NHID, dec_W, 0, NTOK, dec_b, 0,
            out + (size_t)c * CHUNK * BATCH * NTOK, 0, NTOK, CHUNK * BATCH, NTOK, NHID);
    }
}

// Round 3
// 15847.673 us; speedup vs baseline: 1.6697x; 1.6697x over previous
//
#include <hip/hip_runtime.h>
#include <math.h>

#define T_STEPS 128
#define BATCH   512
#define NTOK    512
#define NINP    512
#define NHID    600
#define NBK     6
#define BS      100
#define HH      4
#define DK      64
#define DV      85
#define ATT     340
#define H2      4
#define DK2     32
#define DV2     32
#define KVN     596
#define KVP     640
#define G3      300
#define DECKP   640

typedef __attribute__((ext_vector_type(8))) short short8;
typedef __attribute__((ext_vector_type(4))) float f32x4;

__device__ __forceinline__ float sigf(float x) { return 1.f / (1.f + expf(-x)); }
__device__ __forceinline__ unsigned short f2b(float f) {
    unsigned u = __float_as_uint(f);
    unsigned r = (u + 0x7fffu + ((u >> 16) & 1u)) >> 16;
    return (unsigned short)r;
}

struct ZOff { int div; long s1; long s2; };
__device__ __forceinline__ long zoff(ZOff z, int bz) {
    return (long)(bz / z.div) * z.s1 + (long)(bz % z.div) * z.s2;
}

// ============ fp32 SGEMM: C[M,N] = A@B (+bias), BM=128 BN=64 BK=16 ============
// M must be a multiple of 128. N,K arbitrary (guarded). Row-major A[M,lda], B[K,ldb].
__global__ __launch_bounds__(256) void sgemm(
    const float* __restrict__ A, ZOff za, long aoff, int lda,
    const float* __restrict__ B, ZOff zb, int ldb,
    float* __restrict__ C, ZOff zc, int ldc,
    const float* __restrict__ bias, ZOff zbias,
    int M, int N, int K)
{
    const int bz = blockIdx.z;
    A += zoff(za, bz) + aoff;
    B += zoff(zb, bz);
    C += zoff(zc, bz);
    const float* bp = bias ? bias + zoff(zbias, bz) : nullptr;
    const int m0 = blockIdx.y * 128, n0 = blockIdx.x * 64;
    __shared__ float As[16][132];
    __shared__ float Bs[16][68];
    const int tid = threadIdx.x;
    const int tm = tid >> 4, tn = tid & 15;
    const int ar = tid >> 1, ak = (tid & 1) * 8;   // A staging: row 0..127, k-seg 0/8
    const int bk = tid >> 4, bn = (tid & 15) * 4;  // B staging: k 0..15, n-seg

    float acc[8][4];
#pragma unroll
    for (int i = 0; i < 8; i++)
#pragma unroll
        for (int j = 0; j < 4; j++) acc[i][j] = 0.f;

    for (int k0 = 0; k0 < K; k0 += 16) {
        float av[8], bv[4];
#pragma unroll
        for (int j = 0; j < 8; j++) {
            int gk = k0 + ak + j;
            av[j] = (gk < K) ? A[(long)(m0 + ar) * lda + gk] : 0.f;
        }
#pragma unroll
        for (int j = 0; j < 4; j++) {
            int gk = k0 + bk, gn = n0 + bn + j;
            bv[j] = (gk < K && gn < N) ? B[(long)gk * ldb + gn] : 0.f;
        }
        __syncthreads();
#pragma unroll
        for (int j = 0; j < 8; j++) As[ak + j][ar] = av[j];
#pragma unroll
        for (int j = 0; j < 4; j++) Bs[bk][bn + j] = bv[j];
        __syncthreads();
#pragma unroll
        for (int kk = 0; kk < 16; kk++) {
            float a[8], b[4];
#pragma unroll
            for (int i = 0; i < 8; i++) a[i] = As[kk][tm * 8 + i];
#pragma unroll
            for (int j = 0; j < 4; j++) b[j] = Bs[kk][tn * 4 + j];
#pragma unroll
            for (int i = 0; i < 8; i++)
#pragma unroll
                for (int j = 0; j < 4; j++)
                    acc[i][j] += a[i] * b[j];
        }
    }
#pragma unroll
    for (int i = 0; i < 8; i++) {
        int gm = m0 + tm * 8 + i;
#pragma unroll
        for (int j = 0; j < 4; j++) {
            int gn = n0 + tn * 4 + j;
            if (gn < N) {
                float v = acc[i][j];
                if (bp) v += bp[gn];
                C[(long)gm * ldc + gn] = v;
            }
        }
    }
}

// ============ bf16 MFMA GEMM (decoder only): C = A@B^T + bias, fp32 out ============
// M,N multiples of 128; Kp multiple of 64. B stored transposed [N][Kp].
__global__ __launch_bounds__(256) void gemm_mfma(
    const unsigned short* __restrict__ A,
    const unsigned short* __restrict__ B,
    float* __restrict__ C,
    const float* __restrict__ bias,
    int Kp, int ldc)
{
    const int m0 = blockIdx.y * 128, n0 = blockIdx.x * 128;
    __shared__ __align__(16) unsigned short As[128 * 64];
    __shared__ __align__(16) unsigned short Bs[128 * 64];
    const int tid = threadIdx.x;
    const int lane = tid & 63;
    const int wid = tid >> 6;
    const int wr = wid >> 1, wc = wid & 1;

    f32x4 acc[4][4];
#pragma unroll
    for (int m = 0; m < 4; m++)
#pragma unroll
        for (int n = 0; n < 4; n++)
#pragma unroll
            for (int v = 0; v < 4; v++) acc[m][n][v] = 0.f;

    for (int k0 = 0; k0 < Kp; k0 += 64) {
        short8 ra[4], rb[4];
#pragma unroll
        for (int p = 0; p < 4; p++) {
            int idx = (p << 8) + tid;
            int r = idx >> 3, ce = (idx & 7) << 3;
            ra[p] = *(const short8*)&A[(long)(m0 + r) * Kp + k0 + ce];
            rb[p] = *(const short8*)&B[(long)(n0 + r) * Kp + k0 + ce];
        }
        __syncthreads();
#pragma unroll
        for (int p = 0; p < 4; p++) {
            int idx = (p << 8) + tid;
            int r = idx >> 3, ce = (idx & 7) << 3;
            *(short8*)&As[r * 64 + ce] = ra[p];
            *(short8*)&Bs[r * 64 + ce] = rb[p];
        }
        __syncthreads();
#pragma unroll
        for (int kk = 0; kk < 2; kk++) {
            short8 af[4], bfr[4];
#pragma unroll
            for (int m = 0; m < 4; m++)
                af[m] = *(const short8*)&As[(wr * 64 + m * 16 + (lane & 15)) * 64 + kk * 32 + (lane >> 4) * 8];
#pragma unroll
            for (int n = 0; n < 4; n++)
                bfr[n] = *(const short8*)&Bs[(wc * 64 + n * 16 + (lane & 15)) * 64 + kk * 32 + (lane >> 4) * 8];
#pragma unroll
            for (int m = 0; m < 4; m++)
#pragma unroll
                for (int n = 0; n < 4; n++)
                    acc[m][n] = __builtin_amdgcn_mfma_f32_16x16x32_bf16(af[m], bfr[n], acc[m][n], 0, 0, 0);
        }
    }
#pragma unroll
    for (int m = 0; m < 4; m++) {
        int rbase = m0 + wr * 64 + m * 16 + (lane >> 4) * 4;
#pragma unroll
        for (int n = 0; n < 4; n++) {
            int col = n0 + wc * 64 + n * 16 + (lane & 15);
            float bv = bias ? bias[col] : 0.f;
#pragma unroll
            for (int v = 0; v < 4; v++)
                C[(long)(rbase + v) * ldc + col] = acc[m][n][v] + bv;
        }
    }
}

// ============ small prep kernels ============
__global__ __launch_bounds__(256) void kvb_kernel(const float* __restrict__ enc_b,
                                                  const float* __restrict__ Wk,
                                                  const float* __restrict__ Wv,
                                                  float* __restrict__ kvb)
{
    int j = blockIdx.x * 256 + threadIdx.x;
    if (j >= KVP) return;
    float acc = 0.f;
    if (j < HH * DK) {
        for (int d = 0; d < NINP; d++) acc += enc_b[d] * Wk[d * (HH * DK) + j];
    } else if (j < KVN) {
        int c = j - HH * DK;
        for (int d = 0; d < NINP; d++) acc += enc_b[d] * Wv[d * (HH * DV) + c];
    }
    kvb[j] = acc;
}

// WqT[4][64][100]: WqT[h][d][w] = Wq_in[w][h*64+d]
__global__ __launch_bounds__(256) void prep_wqt(const float* __restrict__ Wq_in,
                                                float* __restrict__ WqT)
{
    int idx = blockIdx.x * 256 + threadIdx.x;
    if (idx >= HH * DK * BS) return;
    int h = idx / (DK * BS), r = idx - h * DK * BS, d = r / BS, w = r - d * BS;
    WqT[idx] = Wq_in[w * (HH * DK) + h * DK + d];
}

// B_dec[512][640] bf16: dst[n][k] = k<600 ? dec_W[k*512+n] : 0
__global__ __launch_bounds__(256) void cvt_dec(const float* __restrict__ dec_W,
                                               unsigned short* __restrict__ dst)
{
    int idx = blockIdx.x * 256 + threadIdx.x;
    if (idx >= NTOK * DECKP) return;
    int n = idx / DECKP, k = idx - n * DECKP;
    dst[idx] = f2b(k < NHID ? dec_W[k * NTOK + n] : 0.f);
}

// ============ serial-path kernel 1: attention + top-k + gi combine ============
__global__ __launch_bounds__(256) void attn_step(
    const float* __restrict__ h_prev,       // [512,600]
    const float* __restrict__ masks_t,      // [512]
    const float* __restrict__ kap,          // [MU,400]
    const float* __restrict__ U,            // [24,MU,300]
    const float* __restrict__ b_ih,         // [6,300]
    float* __restrict__ hb_out,             // [512,600]
    float* __restrict__ gi_out,             // [512,1800]
    float* __restrict__ mask_out,           // [512,6]
    int s, int MU)
{
    const int b = blockIdx.x, tid = threadIdx.x;
    __shared__ float hb[NHID];
    __shared__ float kp[400];
    __shared__ float part[96];
    __shared__ float att[24], acts[NBK];
    __shared__ float kthv;

    const long rowd = (long)s * BATCH + b;
    const float mt = masks_t[b];
    for (int i = tid; i < NHID; i += 256) {
        float v = h_prev[(long)b * NHID + i] * mt;
        hb[i] = v;
        hb_out[(long)b * NHID + i] = v;
    }
    for (int i = tid; i < 400; i += 256) kp[i] = kap[rowd * 400 + i];
    __syncthreads();
    if (tid < 96) {
        int pair = tid >> 2, pi = tid & 3;     // pair = n*4+h
        int n = pair >> 2, h = pair & 3;
        float s0 = 0.f;
        int w0 = pi * 25;
        for (int w = w0; w < w0 + 25; w++) s0 += hb[n * BS + w] * kp[h * BS + w];
        part[tid] = s0;
    }
    __syncthreads();
    if (tid < 24) {
        float lg = part[tid * 4] + part[tid * 4 + 1] + part[tid * 4 + 2] + part[tid * 4 + 3];
        att[tid] = sigf(lg * 0.125f);          // softmax([l,0])[0] == sigmoid(l)
    }
    __syncthreads();
    if (tid < NBK)
        acts[tid] = 0.25f * (att[tid * 4] + att[tid * 4 + 1] + att[tid * 4 + 2] + att[tid * 4 + 3]);
    __syncthreads();
    if (tid == 0) {
        float a[NBK];
        for (int i = 0; i < NBK; i++) a[i] = acts[i];
        for (int i = 0; i < 4; i++) {
            int mx = i;
            for (int j = i + 1; j < NBK; j++) if (a[j] > a[mx]) mx = j;
            float t = a[i]; a[i] = a[mx]; a[mx] = t;
        }
        kthv = a[3];
    }
    __syncthreads();
    if (tid < NBK) mask_out[(long)b * NBK + tid] = (acts[tid] >= kthv) ? 1.f : 0.f;
    for (int idx = tid; idx < NBK * G3; idx += 256) {
        int n = idx / G3, e = idx - n * G3;
        float g = b_ih[n * G3 + e];
#pragma unroll
        for (int h = 0; h < HH; h++)
            g += att[n * 4 + h] * U[((long)(h * NBK + n) * MU + rowd) * G3 + e];
        gi_out[(long)b * (NBK * G3) + idx] = g;
    }
}

// ============ serial-path kernel 3: GRU pointwise + communication attention ============
__global__ __launch_bounds__(256) void gru_comm(
    const float* __restrict__ gi, const float* __restrict__ gh,
    const float* __restrict__ hb_in, const float* __restrict__ mask_in,
    const float* __restrict__ Wq_c, const float* __restrict__ Wk_c,
    const float* __restrict__ Wv_c, const float* __restrict__ Wo_c,
    float* __restrict__ h_out, unsigned short* __restrict__ A_dec, int s)
{
    const int b = blockIdx.x, tid = threadIdx.x;
    __shared__ float hn[NHID], hbs[NHID];
    __shared__ float qc[NBK * 128], kc[NBK * 128], vc[NBK * 128], co[NBK * 128];
    __shared__ float lg[H2 * NBK * NBK];
    __shared__ float mk[NBK];

    const long rowd = (long)s * BATCH + b;
    for (int i = tid; i < NHID; i += 256) {
        int n = i / BS, w = i - n * BS;
        long base = (long)b * (NBK * G3) + n * G3;
        float r = sigf(gi[base + w] + gh[base + w]);
        float z = sigf(gi[base + BS + w] + gh[base + BS + w]);
        float ng = tanhf(gi[base + 2 * BS + w] + r * gh[base + 2 * BS + w]);
        float hbv = hb_in[(long)b * NHID + i];
        hbs[i] = hbv;
        hn[i] = (1.f - z) * ng + z * hbv;
    }
    if (tid < NBK) mk[tid] = mask_in[(long)b * NBK + tid];
    __syncthreads();
    for (int idx = tid; idx < 3 * NBK * 128; idx += 256) {
        int mat = idx / (NBK * 128), r2 = idx - mat * (NBK * 128);
        int n = r2 >> 7, c = r2 & 127;
        const float* W = (mat == 0) ? Wq_c : ((mat == 1) ? Wk_c : Wv_c);
        float a = 0.f;
        for (int d = 0; d < BS; d++) a += hn[n * BS + d] * W[d * 128 + c];
        float* dst = (mat == 0) ? qc : ((mat == 1) ? kc : vc);
        dst[n * 128 + c] = a;
    }
    __syncthreads();
    if (tid < H2 * NBK * NBK) {
        int h = tid / 36, r2 = tid - h * 36, n = r2 / NBK, m = r2 - n * NBK;
        float sv = 0.f;
        for (int e = 0; e < DK2; e++) sv += qc[n * 128 + h * DK2 + e] * kc[m * 128 + h * DK2 + e];
        lg[h * 36 + n * NBK + m] = sv * 0.17677669529663687f;
    }
    __syncthreads();
    if (tid < H2 * NBK) {
        int h = tid / NBK, n = tid - h * NBK;
        float* row = &lg[h * 36 + n * NBK];
        float mx = row[0];
        for (int m = 1; m < NBK; m++) mx = fmaxf(mx, row[m]);
        float sv = 0.f;
        for (int m = 0; m < NBK; m++) { row[m] = expf(row[m] - mx); sv += row[m]; }
        float inv = 1.f / sv;
        for (int m = 0; m < NBK; m++) row[m] *= inv;
    }
    __syncthreads();
    for (int idx = tid; idx < NBK * 128; idx += 256) {
        int n = idx >> 7, d = idx & 127, h = d >> 5;
        float a = 0.f;
        for (int m = 0; m < NBK; m++) a += lg[h * 36 + n * NBK + m] * vc[m * 128 + d];
        co[idx] = a;
    }
    __syncthreads();
    for (int i = tid; i < DECKP; i += 256) {
        float hf = 0.f;
        if (i < NHID) {
            int n = i / BS, w = i - n * BS;
            float a = 0.f;
            for (int d = 0; d < 128; d++) a += co[n * 128 + d] * Wo_c[d * BS + w];
            float hc = hn[i] + a;
            hf = (mk[n] > 0.5f) ? hc : hbs[i];
            h_out[(long)b * NHID + i] = hf;
        }
        A_dec[rowd * DECKP + i] = f2b(hf);
    }
}

// ============ host launch ============
extern "C" void kernel_launch(void* const* d_in, const int* in_sizes, int n_in,
                              void* d_out, int out_size, void* d_ws, size_t ws_size,
                              hipStream_t stream)
{
    const float* input = (const float*)d_in[0];
    const float* h0    = (const float*)d_in[1];
    const float* masks = (const float*)d_in[2];
    const float* enc_W = (const float*)d_in[3];
    const float* enc_b = (const float*)d_in[4];
    const float* Wq_in = (const float*)d_in[5];
    const float* Wk_in = (const float*)d_in[6];
    const float* Wv_in = (const float*)d_in[7];
    const float* W_ih  = (const float*)d_in[8];
    const float* W_hh  = (const float*)d_in[9];
    const float* b_ih  = (const float*)d_in[10];
    const float* b_hh  = (const float*)d_in[11];
    const float* Wq_c  = (const float*)d_in[12];
    const float* Wk_c  = (const float*)d_in[13];
    const float* Wv_c  = (const float*)d_in[14];
    const float* Wo_c  = (const float*)d_in[15];
    const float* dec_W = (const float*)d_in[16];
    const float* dec_b = (const float*)d_in[17];
    float* out = (float*)d_out;

    const size_t AL = 256;
    auto pad = [&](size_t x) { return (x + AL - 1) & ~(AL - 1); };
    size_t fixedB = pad((size_t)NTOK * KVP * 4)        // EWf
                  + pad((size_t)KVP * 4)               // kvb
                  + pad((size_t)HH * DK * BS * 4)      // WqT
                  + pad((size_t)NTOK * DECKP * 2)      // B_dec
                  + 2 * pad((size_t)BATCH * NHID * 4)  // hA,hB
                  + pad((size_t)BATCH * NHID * 4)      // hb_out
                  + 2 * pad((size_t)BATCH * NBK * G3 * 4) // gi, gh
                  + pad((size_t)BATCH * NBK * 4);      // mask
    auto perC = [&](int C) {
        size_t MU = (size_t)C * BATCH;
        return pad(MU * KVP * 4)                 // kvch
             + pad(MU * 400 * 4)                 // kappa
             + pad((size_t)24 * MU * G3 * 4)     // U
             + pad(MU * DECKP * 2);              // A_dec
    };
    int C = 8;
    while (C > 1 && fixedB + perC(C) > ws_size) C >>= 1;
    const int MU = C * BATCH;
    const int NCH = T_STEPS / C;

    char* p = (char*)d_ws;
    auto alloc = [&](size_t bytes) { char* r = p; p += pad(bytes); return r; };
    float*          EWf   = (float*)alloc((size_t)NTOK * KVP * 4);
    float*          kvb   = (float*)alloc((size_t)KVP * 4);
    float*          WqT   = (float*)alloc((size_t)HH * DK * BS * 4);
    unsigned short* B_dec = (unsigned short*)alloc((size_t)NTOK * DECKP * 2);
    float*          hA    = (float*)alloc((size_t)BATCH * NHID * 4);
    float*          hB    = (float*)alloc((size_t)BATCH * NHID * 4);
    float*          hbo   = (float*)alloc((size_t)BATCH * NHID * 4);
    float*          gi    = (float*)alloc((size_t)BATCH * NBK * G3 * 4);
    float*          gh    = (float*)alloc((size_t)BATCH * NBK * G3 * 4);
    float*          mskb  = (float*)alloc((size_t)BATCH * NBK * 4);
    float*          kvch  = (float*)alloc((size_t)MU * KVP * 4);
    float*          kap   = (float*)alloc((size_t)MU * 400 * 4);
    float*          Ubuf  = (float*)alloc((size_t)24 * MU * G3 * 4);
    unsigned short* A_dec = (unsigned short*)alloc((size_t)MU * DECKP * 2);

    dim3 blk(256);
    ZOff z0 = {1, 0, 0};

    // ---- setup ----
    // EWf[:,0:256] = enc_W @ Wk_in ; EWf[:,256:596] = enc_W @ Wv_in (cols 596+ never read)
    sgemm<<<dim3(4, NTOK / 128, 1), blk, 0, stream>>>(
        enc_W, z0, 0, NINP, Wk_in, z0, HH * DK, EWf, z0, KVP,
        nullptr, z0, NTOK, HH * DK, NINP);
    sgemm<<<dim3(6, NTOK / 128, 1), blk, 0, stream>>>(
        enc_W, z0, 0, NINP, Wv_in, z0, HH * DV, EWf + HH * DK, z0, KVP,
        nullptr, z0, NTOK, HH * DV, NINP);
    kvb_kernel<<<dim3((KVP + 255) / 256), blk, 0, stream>>>(enc_b, Wk_in, Wv_in, kvb);
    prep_wqt<<<dim3((HH * DK * BS + 255) / 256), blk, 0, stream>>>(Wq_in, WqT);
    cvt_dec<<<dim3((NTOK * DECKP + 255) / 256), blk, 0, stream>>>(dec_W, B_dec);

    const float* hp = h0;
    float* hbufs[2] = { hA, hB };
    int t = 0;
    for (int c = 0; c < NCH; c++) {
        const float* inc = input + (size_t)c * MU * NTOK;
        // kv: [MU,512] @ EWf[512,596(640)] + kvb -> kvch[MU,640] (cols 596+ unread)
        sgemm<<<dim3(10, MU / 128, 1), blk, 0, stream>>>(
            inc, z0, 0, NTOK, EWf, z0, KVP, kvch, z0, KVP,
            kvb, z0, MU, KVN, NTOK);
        // kappa: z=h: kvch[:, h*64:+64] @ WqT[h] -> kap[:, h*100:+100]
        sgemm<<<dim3(2, MU / 128, HH), blk, 0, stream>>>(
            kvch, ZOff{1, DK, 0}, 0, KVP, WqT, ZOff{1, (long)DK * BS, 0}, BS,
            kap, ZOff{1, BS, 0}, 400, nullptr, z0, MU, BS, DK);
        // U: z=h*6+n: v[:,h] @ W_ih[n, h-slice] -> U[z]
        sgemm<<<dim3(5, MU / 128, HH * NBK), blk, 0, stream>>>(
            kvch, ZOff{NBK, DV, 0}, HH * DK, KVP,
            W_ih, ZOff{NBK, (long)DV * G3, (long)ATT * G3}, G3,
            Ubuf, ZOff{1, (long)MU * G3, 0}, G3,
            nullptr, z0, MU, G3, DV);
        for (int s = 0; s < C; s++, t++) {
            float* hout = hbufs[t & 1];
            attn_step<<<dim3(BATCH), blk, 0, stream>>>(
                hp, masks + (size_t)t * BATCH, kap, Ubuf, b_ih, hbo, gi, mskb, s, MU);
            // gh: z=n: hbo[:, n*100:+100] @ W_hh[n] + b_hh[n] -> gh[:, n*300:+300]
            sgemm<<<dim3(5, BATCH / 128, NBK), blk, 0, stream>>>(
                hbo, ZOff{1, BS, 0}, 0, NHID, W_hh, ZOff{1, (long)BS * G3, 0}, G3,
                gh, ZOff{1, G3, 0}, NBK * G3, b_hh, ZOff{1, G3, 0},
                BATCH, G3, BS);
            gru_comm<<<dim3(BATCH), blk, 0, stream>>>(
                gi, gh, hbo, mskb, Wq_c, Wk_c, Wv_c, Wo_c, hout, A_dec, s);
            hp = hout;
        }
        // decoder: A_dec[MU,640] @ B_dec^T + dec_b -> out
        gemm_mfma<<<dim3(NTOK / 128, MU / 128, 1), blk, 0, stream>>>(
            A_dec, B_dec, out + (size_t)c * MU * NTOK, dec_b, DECKP, NTOK);
    }
}